// Round 13
// baseline (494.067 us; speedup 1.0000x reference)
//
#include <hip/hip_runtime.h>

// MemoryProjection: x_t = A x_{t-1} + in_t * Bd, out = all states (2048,8,64,64) fp32.
// Chunked: out[j*64+tau] = A^(tau+1) x0_j + sum_{k<=tau} (A^(tau-k) Bd) in[j*64+k]
// => one fp16 MFMA GEMM: C[m=(j,q)][nn=(tau,n)] = R16[m][:] . W16[nn][:], K=256
//    R16 = [in(64) | x0h(64) | x0h(64) | x0l(64)], W16 = [Kmat | Ph | Pl | Ph]
// kAB (FUSED, 240 blocks x 1024 thr, 92KB LDS -> 1 block/CU -> all 240 co-resident
//     on 256 CUs regardless of dispatch order):
//   blocks   0..63 : power chains (h/l MFMA) -> W16 Ph/Pl, Kv, A64; then
//                    __threadfence + agent-scope release atomicAdd(flag).
//   blocks  64..191: input transpose -> R16[:,0:64) (independent, overlaps chains).
//   blocks 192..223: fused conv+scan (16 waves = 16 q-cols each) -- acquire-spin
//                    until flag==64 (needs Kv+A64), then r10-identical scan.
//   blocks 224..239: W16 Kmat rows (4 tau each) -- same spin on flag.
//   flag (4B in ws) is hipMemsetAsync'd to 0 each call (deterministic).
// kC: r10 verbatim: BK=32 dbuf, counted vmcnt(4), raw barriers, LDS-staged nt epilogue.
// r11/r12 lessons: direct 64B-granule stores -28us worse (staging stays);
// Tin coalescing null (scan loads weren't the cost) -> dropped.

typedef _Float16 f16;
typedef __attribute__((ext_vector_type(8))) _Float16 f16x8;
typedef __attribute__((ext_vector_type(4))) float f32x4;

// ---------------- kAB: chains | transpose | scan | Kmat ----------------
__global__ __launch_bounds__(1024) void kAB_prep(
    const float* __restrict__ A, const float* __restrict__ Bm,
    const float* __restrict__ inp,
    float* __restrict__ A64, float* __restrict__ Kv,
    f16* __restrict__ W16, f16* __restrict__ R16, int* __restrict__ flag)
{
  __shared__ __align__(16) char sA[92160];   // 10 x 9216B, carved below
  int t = threadIdx.x;
  int blk = blockIdx.x;

  if (blk >= 64 && blk < 192) {
    // -------- transpose: one (j,qb) 64x128 tile --------
    float (*tile)[132] = (float (*)[132])sA;
    int bb = blk - 64;
    int j = bb >> 2, qb = (bb & 3) * 128;
    {
      int k = t >> 4, seg = (t & 15) * 8;
      const float* src = inp + j * 32768 + k * 512 + qb + seg;
      *(f32x4*)(&tile[k][seg])     = *(const f32x4*)(src);
      *(f32x4*)(&tile[k][seg + 4]) = *(const f32x4*)(src + 4);
    }
    __syncthreads();
    {
      int q = t & 127, ks8 = (t >> 7) * 8;
      f16 tmp[8];
      #pragma unroll
      for (int kk = 0; kk < 8; ++kk)
        tmp[kk] = (f16)tile[ks8 + kk][q];
      *(f16x8*)(R16 + ((size_t)(j * 512 + qb + q)) * 256 + ks8) =
          *(const f16x8*)tmp;
    }
    return;
  }

  if (blk >= 192) {
    // -------- consumers: wait for all 64 chain blocks --------
    if (t == 0) {
      long it = 0;
      while (__hip_atomic_load(flag, __ATOMIC_ACQUIRE,
                               __HIP_MEMORY_SCOPE_AGENT) < 64) {
        __builtin_amdgcn_s_sleep(8);
        if (++it > 200000000L) break;   // safety valve, practically unreachable
      }
    }
    __syncthreads();

    if (blk < 224) {
      // -------- fused conv+scan: 16 waves, one q column each --------
      float* smF = (float*)sA;
      int wv = t >> 6, L = t & 63;
      int q = (blk - 192) * 16 + wv;
      float* xs = smF + wv * 144;
      float* vs = xs + 72;
      float ar[64], kvr[64];
      #pragma unroll
      for (int m = 0; m < 64; m += 4) {
        f32x4 v4 = *(const f32x4*)(A64 + L * 64 + m);
        ar[m] = v4.x; ar[m + 1] = v4.y; ar[m + 2] = v4.z; ar[m + 3] = v4.w;
      }
      #pragma unroll
      for (int k = 0; k < 64; ++k) kvr[k] = Kv[(63 - k) * 64 + L];
      float x = 0.f;
      float v = inp[(size_t)L * 512 + q];
      for (int j = 0; j < 32; ++j) {
        float vn = (j < 31) ? inp[(size_t)((j + 1) * 64 + L) * 512 + q] : 0.f;
        f16 hh = (f16)x, ll = (f16)(x - (float)hh);
        f16* row = R16 + ((size_t)(j * 512 + q)) * 256;
        row[64 + L] = hh; row[128 + L] = hh; row[192 + L] = ll;
        xs[L] = x;
        vs[L] = v;
        float a0 = 0.f, a1 = 0.f, c0 = 0.f, c1 = 0.f;
        #pragma unroll
        for (int m = 0; m < 64; m += 4) {
          f32x4 xv = *(const f32x4*)(xs + m);   // same-addr broadcast
          f32x4 vv = *(const f32x4*)(vs + m);
          a0 += ar[m] * xv.x + ar[m + 1] * xv.y;
          a1 += ar[m + 2] * xv.z + ar[m + 3] * xv.w;
          c0 += kvr[m] * vv.x + kvr[m + 1] * vv.y;
          c1 += kvr[m + 2] * vv.z + kvr[m + 3] * vv.w;
        }
        x = (a0 + a1) + (c0 + c1);
        v = vn;
      }
    } else {
      // -------- Kmat rows: 4 tau per block --------
      float* KT = (float*)sA;             // 16 KB
      for (int idx = t; idx < 4096; idx += 1024) KT[idx] = Kv[idx];
      __syncthreads();
      int tau = (blk - 224) * 4 + (t >> 8);
      int sub = t & 255;
      int wn = sub & 63, kq = sub >> 6;
      f16* wrow = W16 + ((size_t)(tau * 64 + wn)) * 256 + kq * 16;
      #pragma unroll
      for (int ki = 0; ki < 16; ++ki) {
        int k = kq * 16 + ki;
        wrow[ki] = (f16)((k <= tau) ? KT[(tau - k) * 64 + wn] : 0.0f);
      }
    }
    return;
  }

  // -------- chain blocks 0..63 --------
  f16 (*Ah)[72]  = (f16 (*)[72])(sA + 0 * 9216);
  f16 (*Al)[72]  = (f16 (*)[72])(sA + 1 * 9216);
  f16 (*B0h)[72] = (f16 (*)[72])(sA + 2 * 9216);
  f16 (*B0l)[72] = (f16 (*)[72])(sA + 3 * 9216);
  f16 (*B1h)[72] = (f16 (*)[72])(sA + 4 * 9216);
  f16 (*B1l)[72] = (f16 (*)[72])(sA + 5 * 9216);
  f16 (*Y8h)[72] = (f16 (*)[72])(sA + 6 * 9216);
  f16 (*Y8l)[72] = (f16 (*)[72])(sA + 7 * 9216);
  f16 (*Ybh)[72] = (f16 (*)[72])(sA + 8 * 9216);
  f16 (*Ybl)[72] = (f16 (*)[72])(sA + 9 * 9216);

  int tau = blk;
  int e = tau + 1;
  int a = e >> 3, b = e & 7;
  int wave = t >> 6, lane = t & 63;
  int tn = wave >> 2, tm = wave & 3;       // 4x4 grid of 16x16 tiles
  int kg = lane >> 4, fr = lane & 15;

  auto mm = [&](f16 (*Ph)[72], f16 (*Pl)[72], f16 (*Qh)[72], f16 (*Ql)[72],
                f16 (*Dh)[72], f16 (*Dl)[72]) {
    f32x4 acc = {};
    #pragma unroll
    for (int kk = 0; kk < 2; ++kk) {
      f16x8 ah = *(const f16x8*)&Ph[tn * 16 + fr][kk * 32 + kg * 8];
      f16x8 al = *(const f16x8*)&Pl[tn * 16 + fr][kk * 32 + kg * 8];
      f16x8 bh = *(const f16x8*)&Qh[tm * 16 + fr][kk * 32 + kg * 8];
      f16x8 bl = *(const f16x8*)&Ql[tm * 16 + fr][kk * 32 + kg * 8];
      acc = __builtin_amdgcn_mfma_f32_16x16x32_f16(ah, bh, acc, 0, 0, 0);
      acc = __builtin_amdgcn_mfma_f32_16x16x32_f16(ah, bl, acc, 0, 0, 0);
      acc = __builtin_amdgcn_mfma_f32_16x16x32_f16(al, bh, acc, 0, 0, 0);
    }
    #pragma unroll
    for (int r = 0; r < 4; ++r) {
      float v = acc[r];
      f16 h = (f16)v, l = (f16)(v - (float)h);
      Dh[tn * 16 + kg * 4 + r][tm * 16 + fr] = h;
      Dl[tn * 16 + kg * 4 + r][tm * 16 + fr] = l;
    }
    __syncthreads();
  };
  auto cpy2 = [&](f16 (*Sh)[72], f16 (*Sl)[72], f16 (*Dh)[72], f16 (*Dl)[72]) {
    const unsigned* sh = (const unsigned*)Sh; unsigned* dh = (unsigned*)Dh;
    const unsigned* sl = (const unsigned*)Sl; unsigned* dl = (unsigned*)Dl;
    for (int idx = t; idx < 2304; idx += 1024) { dh[idx] = sh[idx]; dl[idx] = sl[idx]; }
  };

  for (int idx = t; idx < 4096; idx += 1024) {
    float v = A[idx];
    int r = idx >> 6, c2 = idx & 63;
    f16 h = (f16)v, l = (f16)(v - (float)h);
    Ah[r][c2] = h;  Al[r][c2] = l;
    B0h[c2][r] = h; B0l[c2][r] = l;
  }
  __syncthreads();

  f16 (*curH)[72] = B0h; f16 (*curL)[72] = B0l;
  f16 (*othH)[72] = B1h; f16 (*othL)[72] = B1l;
  auto swp = [&]() {
    f16 (*tH)[72] = curH; curH = othH; othH = tH;
    f16 (*tL)[72] = curL; curL = othL; othL = tL;
  };

  if (b == 1) cpy2(curH, curL, Ybh, Ybl);

  int loMax = (a >= 1) ? 8 : b;
  for (int i = 2; i <= loMax; ++i) {
    mm(curH, curL, Ah, Al, othH, othL);
    swp();
    if (i == b) cpy2(curH, curL, Ybh, Ybl);
    if (i == 8) cpy2(curH, curL, Y8h, Y8l);
  }

  f16 (*Rh)[72]; f16 (*Rl)[72]; bool tr;
  if (a == 0) {
    Rh = curH; Rl = curL; tr = true;                // result = Y_b^T
  } else {
    for (int idx = t; idx < 4096; idx += 1024) {
      int i = idx >> 6, j = idx & 63;
      othH[i][j] = curH[j][i];
      othL[i][j] = curL[j][i];
    }
    swp();
    __syncthreads();
    for (int a2 = 2; a2 <= a; ++a2) {               // H_{a+1} = mfma(H_a, Y8)
      mm(curH, curL, Y8h, Y8l, othH, othL);
      swp();
    }
    if (b >= 1) {                                   // P = mfma(H_a, Y_b)
      mm(curH, curL, Ybh, Ybl, othH, othL);
      swp();
    }
    Rh = curH; Rl = curL; tr = false;
  }

  // epilogue: W16 rows [64..128)=Ph, [128..192)=Pl, [192..256)=Ph; A64; Kv
  for (int idx = t; idx < 4096; idx += 1024) {
    int wn = idx >> 6, m = idx & 63;
    f16 h = tr ? Rh[m][wn] : Rh[wn][m];
    f16 l = tr ? Rl[m][wn] : Rl[wn][m];
    f16* wrow = W16 + ((size_t)(tau * 64 + wn)) * 256;
    wrow[64 + m] = h; wrow[128 + m] = l; wrow[192 + m] = h;
    if (tau == 63) A64[idx] = (float)h + (float)l;
  }
  if (t < 64) {
    float s = 0.f;
    #pragma unroll 8
    for (int m = 0; m < 64; ++m) {
      float pv = tr ? ((float)Rh[m][t] + (float)Rl[m][t])
                    : ((float)Rh[t][m] + (float)Rl[t][m]);
      s += pv * Bm[m];
    }
    if (tau < 63) Kv[(tau + 1) * 64 + t] = s;
    else          Kv[t] = Bm[t];
  }

  // publish: Kv/A64 visible device-wide, then bump flag (release, agent scope)
  __threadfence();
  __syncthreads();
  if (t == 0)
    __hip_atomic_fetch_add(flag, 1, __ATOMIC_RELEASE, __HIP_MEMORY_SCOPE_AGENT);
}

// ---------------- kC: C[16384 x 4096] = R16 @ W16^T (r10 verbatim) ----------------
// BK=32, 2 buffers (16KB each: A 8KB + B 8KB), counted vmcnt(4), raw barriers.
// LDS rows 64B: LDS[row][slot] holds G[row][slot ^ ((row>>1)&3)] (slot = 8 f16).
#define STAGE32(ks, dbuf)                                                       \
  { _Pragma("unroll")                                                           \
    for (int it = 0; it < 2; ++it) {                                            \
      __builtin_amdgcn_global_load_lds(                                         \
        (const __attribute__((address_space(1))) void*)                         \
          (R16 + ((size_t)(mtb + w32 + it * 16 + l4)) * 256 + (ks) * 32 + swc32),\
        (__attribute__((address_space(3))) void*)((dbuf) + w * 1024 + it * 512),\
        16, 0, 0);                                                              \
      __builtin_amdgcn_global_load_lds(                                         \
        (const __attribute__((address_space(1))) void*)                         \
          (W16 + ((size_t)(ntb + w32 + it * 16 + l4)) * 256 + (ks) * 32 + swc32),\
        (__attribute__((address_space(3))) void*)((dbuf) + 4096 + w * 1024 + it * 512),\
        16, 0, 0);                                                              \
    } }

#define KSTEP32(sbuf)                                                           \
  { f16x8 af[4], bf[4];                                                         \
    _Pragma("unroll")                                                           \
    for (int i = 0; i < 4; ++i) {                                               \
      af[i] = *(const f16x8*)((sbuf) + (wr * 64 + i * 16 + fr) * 32 + scol);    \
      bf[i] = *(const f16x8*)((sbuf) + 4096 + (wc * 64 + i * 16 + fr) * 32 + scol);\
    }                                                                           \
    _Pragma("unroll")                                                           \
    for (int mi = 0; mi < 4; ++mi)                                              \
      _Pragma("unroll")                                                         \
      for (int ni = 0; ni < 4; ++ni)                                            \
        acc[mi][ni] = __builtin_amdgcn_mfma_f32_16x16x32_f16(                   \
            af[mi], bf[ni], acc[mi][ni], 0, 0, 0);                              \
  }

#define WAITN(n) asm volatile("s_waitcnt vmcnt(" #n ")" ::: "memory")
#define BAR()                                                                   \
  { __builtin_amdgcn_sched_barrier(0); __builtin_amdgcn_s_barrier();            \
    __builtin_amdgcn_sched_barrier(0); }

__global__ __launch_bounds__(256, 4) void kC_gemm(
    const f16* __restrict__ R16, const f16* __restrict__ W16,
    float* __restrict__ out)
{
  __shared__ __align__(16) char smem[34816];     // 2x16KB staging; epilogue alias
  f16* b0v = (f16*)smem;
  f16* b1v = b0v + 8192;
  float (*stg)[68] = (float (*)[68])smem;        // 34816B, aliased

  int wg = blockIdx.x;
  int swz = (wg & 7) * 512 + (wg >> 3);          // XCD-contiguous mt ranges
  int mt = swz >> 5, nt = swz & 31;
  int t = threadIdx.x, w = t >> 6, lane = t & 63;
  int wr = w >> 1, wc = w & 1;
  int kg = lane >> 4, fr = lane & 15;

  // staging indices (BK=32, 64B rows, 4 lanes/row)
  int l4 = lane >> 2;
  int swc32 = 8 * ((lane & 3) ^ ((lane >> 3) & 3));   // pre-swizzled src col (f16)
  int w32 = w * 32;
  int mtb = mt * 128, ntb = nt * 128;
  int scol = 8 * (kg ^ ((fr >> 1) & 3));              // swizzle-matched read col

  f32x4 acc[4][4] = {};

  STAGE32(0, b0v);
  STAGE32(1, b1v); WAITN(4); BAR(); KSTEP32(b0v); BAR();
  STAGE32(2, b0v); WAITN(4); BAR(); KSTEP32(b1v); BAR();
  STAGE32(3, b1v); WAITN(4); BAR(); KSTEP32(b0v); BAR();
  STAGE32(4, b0v); WAITN(4); BAR(); KSTEP32(b1v); BAR();
  STAGE32(5, b1v); WAITN(4); BAR(); KSTEP32(b0v); BAR();
  STAGE32(6, b0v); WAITN(4); BAR(); KSTEP32(b1v); BAR();
  STAGE32(7, b1v); WAITN(4); BAR(); KSTEP32(b0v); BAR();
  WAITN(0); BAR(); KSTEP32(b1v); BAR();

  // epilogue: per tau-half, stage 128x64 f32 tile in LDS, nt-write 32KB contiguous
  int j = mt >> 2, q0 = (mt & 3) * 128;
  #pragma unroll
  for (int half = 0; half < 2; ++half) {
    if (wc == half) {
      #pragma unroll
      for (int mi = 0; mi < 4; ++mi)
        #pragma unroll
        for (int ni = 0; ni < 4; ++ni)
          #pragma unroll
          for (int r = 0; r < 4; ++r)
            stg[wr * 64 + mi * 16 + kg * 4 + r][ni * 16 + fr] = acc[mi][ni][r];
    }
    asm volatile("s_waitcnt lgkmcnt(0)" ::: "memory");
    BAR();
    int tau_g = nt * 2 + half;
    float* obase = out + (size_t)j * 2097152 + (size_t)tau_g * 32768 + (size_t)q0 * 64;
    #pragma unroll
    for (int it = 0; it < 8; ++it) {
      int fi = it * 1024 + t * 4;
      int rr = fi >> 6, cc = fi & 63;
      __builtin_nontemporal_store(*(const f32x4*)(&stg[rr][cc]),
                                  (f32x4*)(obase + fi));
    }
    BAR();
  }
}

extern "C" void kernel_launch(void* const* d_in, const int* in_sizes, int n_in,
                              void* d_out, int out_size, void* d_ws, size_t ws_size,
                              hipStream_t stream)
{
  (void)in_sizes; (void)n_in; (void)out_size; (void)ws_size;
  const float* inp = (const float*)d_in[0];   // (2048, 8, 64) fp32
  const float* A   = (const float*)d_in[1];   // (64, 64) fp32
  const float* Bm  = (const float*)d_in[2];   // (64, 1) fp32
  float* out = (float*)d_out;                 // (2048, 8, 64, 64) fp32

  float* ws = (float*)d_ws;
  float* A64 = ws;                            // 4096 f32   (16 KB)
  float* Kv  = ws + 4096;                     // 4096 f32   (16 KB)
  f16*  W16  = (f16*)(ws + 8192);             // 4096*256 f16 (2 MB)
  f16*  R16  = (f16*)((char*)d_ws + 2129920); // 16384*256 f16 (8 MB)
  int*  flag = (int*)((char*)d_ws + 10518528);// 4 B

  hipMemsetAsync(flag, 0, 4, stream);
  hipLaunchKernelGGL(kAB_prep, dim3(240),  dim3(1024), 0, stream,
                     A, Bm, inp, A64, Kv, W16, R16, flag);
  hipLaunchKernelGGL(kC_gemm,  dim3(4096), dim3(256),  0, stream, R16, W16, out);
}

// Round 14
// 102.424 us; speedup vs baseline: 4.8237x; 4.8237x over previous
//
#include <hip/hip_runtime.h>

// MemoryProjection: x_t = A x_{t-1} + in_t * Bd, out = all states (2048,8,64,64) fp32.
// Chunked: out[j*64+tau] = A^(tau+1) x0_j + sum_{k<=tau} (A^(tau-k) Bd) in[j*64+k]
// => one fp16 MFMA GEMM: C[m=(j,q)][nn=(tau,n)] = R16[m][:] . W16[nn][:], K=256
//    R16 = [in(64) | x0h(64) | x0h(64) | x0l(64)], W16 = [Kmat | Ph | Pl | Ph]
// kA: blocks 0..63 power chains (h/l MFMA); 64..191 input transpose (r10 verbatim;
//     r13's fused spin-wait kernel idled the chip at 447us -- reverted).
// kB: blocks 0..63 W16 Kmat; 64..191 fused conv+scan (LDS-broadcast matvec).
// kC: NEW: 32x32x16 MFMA. C-layout col=lane&31 = 32 consecutive nn -> each acc reg
//     nt-stores as full 128B lines DIRECT from registers: no epilogue LDS staging,
//     no epilogue barriers (r11's direct-store failure was 64B half-lines; 128B
//     lines restore write-combine efficiency). Main loop = r10's staged BK=32 dbuf
//     + counted vmcnt(4) + raw barriers, same both-sides XOR swizzle.

typedef _Float16 f16;
typedef __attribute__((ext_vector_type(8))) _Float16 f16x8;
typedef __attribute__((ext_vector_type(4))) float f32x4;
typedef __attribute__((ext_vector_type(16))) float f32x16;

// ---------------- kA: powers via h/l MFMA (+ transpose blocks) ----------------
__global__ __launch_bounds__(1024) void kA_pow(
    const float* __restrict__ A, const float* __restrict__ Bm,
    const float* __restrict__ inp,
    float* __restrict__ A64, float* __restrict__ Kv,
    f16* __restrict__ W16, f16* __restrict__ R16)
{
  __shared__ __align__(16) char sA[92160];   // 10 x 9216B, carved below
  int t = threadIdx.x;

  if (blockIdx.x >= 64) {
    // -------- transpose: one (j,qb) 64x128 tile, 1024 threads --------
    float (*tile)[132] = (float (*)[132])sA;       // 33792B, aliases chain bufs
    int bb = blockIdx.x - 64;
    int j = bb >> 2, qb = (bb & 3) * 128;
    {
      int k = t >> 4, seg = (t & 15) * 8;
      const float* src = inp + j * 32768 + k * 512 + qb + seg;
      *(f32x4*)(&tile[k][seg])     = *(const f32x4*)(src);
      *(f32x4*)(&tile[k][seg + 4]) = *(const f32x4*)(src + 4);
    }
    __syncthreads();
    {
      int q = t & 127, ks8 = (t >> 7) * 8;
      f16 tmp[8];
      #pragma unroll
      for (int kk = 0; kk < 8; ++kk)
        tmp[kk] = (f16)tile[ks8 + kk][q];
      *(f16x8*)(R16 + ((size_t)(j * 512 + qb + q)) * 256 + ks8) =
          *(const f16x8*)tmp;
    }
    return;
  }

  f16 (*Ah)[72]  = (f16 (*)[72])(sA + 0 * 9216);
  f16 (*Al)[72]  = (f16 (*)[72])(sA + 1 * 9216);
  f16 (*B0h)[72] = (f16 (*)[72])(sA + 2 * 9216);
  f16 (*B0l)[72] = (f16 (*)[72])(sA + 3 * 9216);
  f16 (*B1h)[72] = (f16 (*)[72])(sA + 4 * 9216);
  f16 (*B1l)[72] = (f16 (*)[72])(sA + 5 * 9216);
  f16 (*Y8h)[72] = (f16 (*)[72])(sA + 6 * 9216);
  f16 (*Y8l)[72] = (f16 (*)[72])(sA + 7 * 9216);
  f16 (*Ybh)[72] = (f16 (*)[72])(sA + 8 * 9216);
  f16 (*Ybl)[72] = (f16 (*)[72])(sA + 9 * 9216);

  int tau = blockIdx.x;
  int e = tau + 1;
  int a = e >> 3, b = e & 7;
  int wave = t >> 6, lane = t & 63;
  int tn = wave >> 2, tm = wave & 3;       // 4x4 grid of 16x16 tiles
  int kg = lane >> 4, fr = lane & 15;

  auto mm = [&](f16 (*Ph)[72], f16 (*Pl)[72], f16 (*Qh)[72], f16 (*Ql)[72],
                f16 (*Dh)[72], f16 (*Dl)[72]) {
    f32x4 acc = {};
    #pragma unroll
    for (int kk = 0; kk < 2; ++kk) {
      f16x8 ah = *(const f16x8*)&Ph[tn * 16 + fr][kk * 32 + kg * 8];
      f16x8 al = *(const f16x8*)&Pl[tn * 16 + fr][kk * 32 + kg * 8];
      f16x8 bh = *(const f16x8*)&Qh[tm * 16 + fr][kk * 32 + kg * 8];
      f16x8 bl = *(const f16x8*)&Ql[tm * 16 + fr][kk * 32 + kg * 8];
      acc = __builtin_amdgcn_mfma_f32_16x16x32_f16(ah, bh, acc, 0, 0, 0);
      acc = __builtin_amdgcn_mfma_f32_16x16x32_f16(ah, bl, acc, 0, 0, 0);
      acc = __builtin_amdgcn_mfma_f32_16x16x32_f16(al, bh, acc, 0, 0, 0);
    }
    #pragma unroll
    for (int r = 0; r < 4; ++r) {
      float v = acc[r];
      f16 h = (f16)v, l = (f16)(v - (float)h);
      Dh[tn * 16 + kg * 4 + r][tm * 16 + fr] = h;
      Dl[tn * 16 + kg * 4 + r][tm * 16 + fr] = l;
    }
    __syncthreads();
  };
  auto cpy2 = [&](f16 (*Sh)[72], f16 (*Sl)[72], f16 (*Dh)[72], f16 (*Dl)[72]) {
    const unsigned* sh = (const unsigned*)Sh; unsigned* dh = (unsigned*)Dh;
    const unsigned* sl = (const unsigned*)Sl; unsigned* dl = (unsigned*)Dl;
    for (int idx = t; idx < 2304; idx += 1024) { dh[idx] = sh[idx]; dl[idx] = sl[idx]; }
  };

  for (int idx = t; idx < 4096; idx += 1024) {
    float v = A[idx];
    int r = idx >> 6, c2 = idx & 63;
    f16 h = (f16)v, l = (f16)(v - (float)h);
    Ah[r][c2] = h;  Al[r][c2] = l;
    B0h[c2][r] = h; B0l[c2][r] = l;
  }
  __syncthreads();

  f16 (*curH)[72] = B0h; f16 (*curL)[72] = B0l;
  f16 (*othH)[72] = B1h; f16 (*othL)[72] = B1l;
  auto swp = [&]() {
    f16 (*tH)[72] = curH; curH = othH; othH = tH;
    f16 (*tL)[72] = curL; curL = othL; othL = tL;
  };

  if (b == 1) cpy2(curH, curL, Ybh, Ybl);

  int loMax = (a >= 1) ? 8 : b;
  for (int i = 2; i <= loMax; ++i) {
    mm(curH, curL, Ah, Al, othH, othL);
    swp();
    if (i == b) cpy2(curH, curL, Ybh, Ybl);
    if (i == 8) cpy2(curH, curL, Y8h, Y8l);
  }

  f16 (*Rh)[72]; f16 (*Rl)[72]; bool tr;
  if (a == 0) {
    Rh = curH; Rl = curL; tr = true;                // result = Y_b^T
  } else {
    for (int idx = t; idx < 4096; idx += 1024) {
      int i = idx >> 6, j = idx & 63;
      othH[i][j] = curH[j][i];
      othL[i][j] = curL[j][i];
    }
    swp();
    __syncthreads();
    for (int a2 = 2; a2 <= a; ++a2) {               // H_{a+1} = mfma(H_a, Y8)
      mm(curH, curL, Y8h, Y8l, othH, othL);
      swp();
    }
    if (b >= 1) {                                   // P = mfma(H_a, Y_b)
      mm(curH, curL, Ybh, Ybl, othH, othL);
      swp();
    }
    Rh = curH; Rl = curL; tr = false;
  }

  for (int idx = t; idx < 4096; idx += 1024) {
    int wn = idx >> 6, m = idx & 63;
    f16 h = tr ? Rh[m][wn] : Rh[wn][m];
    f16 l = tr ? Rl[m][wn] : Rl[wn][m];
    f16* wrow = W16 + ((size_t)(tau * 64 + wn)) * 256;
    wrow[64 + m] = h; wrow[128 + m] = l; wrow[192 + m] = h;
    if (tau == 63) A64[idx] = (float)h + (float)l;
  }
  if (t < 64) {
    float s = 0.f;
    #pragma unroll 8
    for (int m = 0; m < 64; ++m) {
      float pv = tr ? ((float)Rh[m][t] + (float)Rl[m][t])
                    : ((float)Rh[t][m] + (float)Rl[t][m]);
      s += pv * Bm[m];
    }
    if (tau < 63) Kv[(tau + 1) * 64 + t] = s;
    else          Kv[t] = Bm[t];
  }
}

// ---------------- kB: Kmat rows | fused conv+scan (LDS-broadcast) ----------------
__global__ __launch_bounds__(256) void kB_prep(
    const float* __restrict__ inp, const float* __restrict__ Kv,
    const float* __restrict__ A64,
    f16* __restrict__ R16, f16* __restrict__ W16)
{
  __shared__ __align__(16) float sm[64 * 66];
  int t = threadIdx.x;
  int b = blockIdx.x;
  if (b < 64) {
    int tau = b;
    for (int idx = t; idx < 4096; idx += 256) sm[idx] = Kv[idx];
    __syncthreads();
    int wn = t & 63, kq = t >> 6;
    f16* wrow = W16 + ((size_t)(tau * 64 + wn)) * 256 + kq * 16;
    #pragma unroll
    for (int ki = 0; ki < 16; ++ki) {
      int k = kq * 16 + ki;
      wrow[ki] = (f16)((k <= tau) ? sm[(tau - k) * 64 + wn] : 0.0f);
    }
  } else {
    int wv = t >> 6, L = t & 63;
    int q = (b - 64) * 4 + wv;
    float* xs = sm + wv * 144;
    float* vs = xs + 72;
    float ar[64], kvr[64];
    #pragma unroll
    for (int m = 0; m < 64; m += 4) {
      f32x4 v4 = *(const f32x4*)(A64 + L * 64 + m);
      ar[m] = v4.x; ar[m + 1] = v4.y; ar[m + 2] = v4.z; ar[m + 3] = v4.w;
    }
    #pragma unroll
    for (int k = 0; k < 64; ++k) kvr[k] = Kv[(63 - k) * 64 + L];
    float x = 0.f;
    float v = inp[(size_t)L * 512 + q];
    for (int j = 0; j < 32; ++j) {
      float vn = (j < 31) ? inp[(size_t)((j + 1) * 64 + L) * 512 + q] : 0.f;
      f16 hh = (f16)x, ll = (f16)(x - (float)hh);
      f16* row = R16 + ((size_t)(j * 512 + q)) * 256;
      row[64 + L] = hh; row[128 + L] = hh; row[192 + L] = ll;
      xs[L] = x;
      vs[L] = v;
      float a0 = 0.f, a1 = 0.f, c0 = 0.f, c1 = 0.f;
      #pragma unroll
      for (int m = 0; m < 64; m += 4) {
        f32x4 xv = *(const f32x4*)(xs + m);   // same-addr broadcast, conflict-free
        f32x4 vv = *(const f32x4*)(vs + m);
        a0 += ar[m] * xv.x + ar[m + 1] * xv.y;
        a1 += ar[m + 2] * xv.z + ar[m + 3] * xv.w;
        c0 += kvr[m] * vv.x + kvr[m + 1] * vv.y;
        c1 += kvr[m + 2] * vv.z + kvr[m + 3] * vv.w;
      }
      x = (a0 + a1) + (c0 + c1);
      v = vn;
    }
  }
}

// ---------------- kC: C[16384 x 4096] = R16 @ W16^T, 32x32x16, direct-line stores ----------------
// BK=32, 2 buffers (16KB each: R 8KB + W 8KB), counted vmcnt(4), raw barriers.
// LDS rows 64B: LDS[row][slot] holds G[row][slot ^ ((row>>1)&3)] (slot = 8 f16).
// Wave w: B-frag = W rows [w*32,w*32+32) (nn), A-frags mc = R rows [mc*32,+32) (m).
// D: m-row = (reg&3)+8*(reg>>2)+4*(lane>>5), nn-col = lane&31 -> stores are
// 2x128B contiguous lines per instruction, no LDS epilogue.
#define STAGE32(ks, dbuf)                                                       \
  { _Pragma("unroll")                                                           \
    for (int it = 0; it < 2; ++it) {                                            \
      __builtin_amdgcn_global_load_lds(                                         \
        (const __attribute__((address_space(1))) void*)                         \
          (R16 + ((size_t)(mtb + w32 + it * 16 + l4)) * 256 + (ks) * 32 + swc32),\
        (__attribute__((address_space(3))) void*)((dbuf) + w * 1024 + it * 512),\
        16, 0, 0);                                                              \
      __builtin_amdgcn_global_load_lds(                                         \
        (const __attribute__((address_space(1))) void*)                         \
          (W16 + ((size_t)(ntb + w32 + it * 16 + l4)) * 256 + (ks) * 32 + swc32),\
        (__attribute__((address_space(3))) void*)((dbuf) + 4096 + w * 1024 + it * 512),\
        16, 0, 0);                                                              \
    } }

#define KSTEP32(sbuf)                                                           \
  { _Pragma("unroll")                                                           \
    for (int kk = 0; kk < 2; ++kk) {                                            \
      int slot = (kk * 2 + l5) ^ sl0;                                           \
      f16x8 bfw = *(const f16x8*)((sbuf) + 4096 + (w * 32 + l31) * 32 + slot * 8);\
      f16x8 afr[4];                                                             \
      _Pragma("unroll")                                                         \
      for (int mc = 0; mc < 4; ++mc)                                            \
        afr[mc] = *(const f16x8*)((sbuf) + (mc * 32 + l31) * 32 + slot * 8);    \
      _Pragma("unroll")                                                         \
      for (int mc = 0; mc < 4; ++mc)                                            \
        acc[mc] = __builtin_amdgcn_mfma_f32_32x32x16_f16(                       \
            afr[mc], bfw, acc[mc], 0, 0, 0);                                    \
    } }

#define WAITN(n) asm volatile("s_waitcnt vmcnt(" #n ")" ::: "memory")
#define BAR()                                                                   \
  { __builtin_amdgcn_sched_barrier(0); __builtin_amdgcn_s_barrier();            \
    __builtin_amdgcn_sched_barrier(0); }

__global__ __launch_bounds__(256, 4) void kC_gemm(
    const f16* __restrict__ R16, const f16* __restrict__ W16,
    float* __restrict__ out)
{
  __shared__ __align__(16) char smem[32768];     // 2x16KB staging only
  f16* b0v = (f16*)smem;
  f16* b1v = b0v + 8192;

  int wg = blockIdx.x;
  int swz = (wg & 7) * 512 + (wg >> 3);          // XCD-contiguous mt ranges
  int mt = swz >> 5, nt = swz & 31;
  int t = threadIdx.x, w = t >> 6, lane = t & 63;
  int l31 = lane & 31, l5 = lane >> 5;
  int sl0 = (l31 >> 1) & 3;

  // staging indices (BK=32, 64B rows, 4 lanes/row)
  int l4 = lane >> 2;
  int swc32 = 8 * ((lane & 3) ^ ((lane >> 3) & 3));   // pre-swizzled src col (f16)
  int w32 = w * 32;
  int mtb = mt * 128, ntb = nt * 128;

  f32x16 acc[4] = {};   // [mc]; 16 regs each

  STAGE32(0, b0v);
  STAGE32(1, b1v); WAITN(4); BAR(); KSTEP32(b0v); BAR();
  STAGE32(2, b0v); WAITN(4); BAR(); KSTEP32(b1v); BAR();
  STAGE32(3, b1v); WAITN(4); BAR(); KSTEP32(b0v); BAR();
  STAGE32(4, b0v); WAITN(4); BAR(); KSTEP32(b1v); BAR();
  STAGE32(5, b1v); WAITN(4); BAR(); KSTEP32(b0v); BAR();
  STAGE32(6, b0v); WAITN(4); BAR(); KSTEP32(b1v); BAR();
  STAGE32(7, b1v); WAITN(4); BAR(); KSTEP32(b0v); BAR();
  WAITN(0); BAR(); KSTEP32(b1v);

  // epilogue: direct nt stores, 2x128B lines per instruction.
  // tau = nt*2 + (w>>1); n = (w&1)*32 + l31; q = (mt&3)*128 + mc*32+(r&3)+8*(r>>2)+4*l5.
  int j = mt >> 2;
  int tau_g = nt * 2 + (w >> 1);
  float* ob = out + (size_t)j * 2097152 + (size_t)tau_g * 32768
            + (size_t)((mt & 3) * 128) * 64 + (size_t)l5 * 256
            + (w & 1) * 32 + l31;
  #pragma unroll
  for (int mc = 0; mc < 4; ++mc)
    #pragma unroll
    for (int r = 0; r < 16; ++r) {
      int qo = mc * 32 + (r & 3) + 8 * (r >> 2);
      __builtin_nontemporal_store(acc[mc][r], ob + (size_t)qo * 64);
    }
}

extern "C" void kernel_launch(void* const* d_in, const int* in_sizes, int n_in,
                              void* d_out, int out_size, void* d_ws, size_t ws_size,
                              hipStream_t stream)
{
  (void)in_sizes; (void)n_in; (void)out_size; (void)ws_size;
  const float* inp = (const float*)d_in[0];   // (2048, 8, 64) fp32
  const float* A   = (const float*)d_in[1];   // (64, 64) fp32
  const float* Bm  = (const float*)d_in[2];   // (64, 1) fp32
  float* out = (float*)d_out;                 // (2048, 8, 64, 64) fp32

  float* ws = (float*)d_ws;
  float* A64 = ws;                            // 4096 f32   (16 KB)
  float* Kv  = ws + 4096;                     // 4096 f32   (16 KB)
  f16*  W16  = (f16*)(ws + 8192);             // 4096*256 f16 (2 MB)
  f16*  R16  = (f16*)((char*)d_ws + 2129920); // 16384*256 f16 (8 MB)

  hipLaunchKernelGGL(kA_pow,  dim3(192),  dim3(1024), 0, stream, A, Bm, inp, A64, Kv, W16, R16);
  hipLaunchKernelGGL(kB_prep, dim3(192),  dim3(256),  0, stream, inp, Kv, A64, R16, W16);
  hipLaunchKernelGGL(kC_gemm, dim3(4096), dim3(256),  0, stream, R16, W16, out);
}

// Round 15
// 100.546 us; speedup vs baseline: 4.9138x; 1.0187x over previous
//
#include <hip/hip_runtime.h>

// MemoryProjection: x_t = A x_{t-1} + in_t * Bd, out = all states (2048,8,64,64) fp32.
// Chunked: out[j*64+tau] = A^(tau+1) x0_j + sum_{k<=tau} (A^(tau-k) Bd) in[j*64+k]
// => one fp16 MFMA GEMM: C[m=(j,q)][nn=(tau,n)] = R16[m][:] . W16[nn][:], K=256
//    R16 = [in(64) | x0h(64) | x0h(64) | x0l(64)], W16 = [Kmat | Ph | Pl | Ph]
// kA: blocks 0..63 power chains (h/l MFMA); 64..191 input transpose -> R16[:,0:64).
// kB: blocks 0..63 W16 Kmat; 64..191 fused conv+scan (LDS-broadcast matvec).
// kC: r10 structure: BK=32 dbuf, counted vmcnt(4), raw barriers, LDS-staged epilogue.
//     SINGLE CHANGE vs r10: epilogue stores are PLAIN (not nontemporal). A/B test:
//     r10/r14 both null on LDS/epilogue variants; the shared element was the nt
//     store path (~4 TB/s effective), while harness fillBuffer hits 6.8 TB/s with
//     normal cached stores on the same buffer. nt was never isolated (r3 bundle).

typedef _Float16 f16;
typedef __attribute__((ext_vector_type(8))) _Float16 f16x8;
typedef __attribute__((ext_vector_type(4))) float f32x4;

// ---------------- kA: powers via h/l MFMA (+ transpose blocks) ----------------
__global__ __launch_bounds__(1024) void kA_pow(
    const float* __restrict__ A, const float* __restrict__ Bm,
    const float* __restrict__ inp,
    float* __restrict__ A64, float* __restrict__ Kv,
    f16* __restrict__ W16, f16* __restrict__ R16)
{
  __shared__ __align__(16) char sA[92160];   // 10 x 9216B, carved below
  int t = threadIdx.x;

  if (blockIdx.x >= 64) {
    // -------- transpose: one (j,qb) 64x128 tile, 1024 threads --------
    float (*tile)[132] = (float (*)[132])sA;       // 33792B, aliases chain bufs
    int bb = blockIdx.x - 64;
    int j = bb >> 2, qb = (bb & 3) * 128;
    {
      int k = t >> 4, seg = (t & 15) * 8;
      const float* src = inp + j * 32768 + k * 512 + qb + seg;
      *(f32x4*)(&tile[k][seg])     = *(const f32x4*)(src);
      *(f32x4*)(&tile[k][seg + 4]) = *(const f32x4*)(src + 4);
    }
    __syncthreads();
    {
      int q = t & 127, ks8 = (t >> 7) * 8;
      f16 tmp[8];
      #pragma unroll
      for (int kk = 0; kk < 8; ++kk)
        tmp[kk] = (f16)tile[ks8 + kk][q];
      *(f16x8*)(R16 + ((size_t)(j * 512 + qb + q)) * 256 + ks8) =
          *(const f16x8*)tmp;
    }
    return;
  }

  f16 (*Ah)[72]  = (f16 (*)[72])(sA + 0 * 9216);
  f16 (*Al)[72]  = (f16 (*)[72])(sA + 1 * 9216);
  f16 (*B0h)[72] = (f16 (*)[72])(sA + 2 * 9216);
  f16 (*B0l)[72] = (f16 (*)[72])(sA + 3 * 9216);
  f16 (*B1h)[72] = (f16 (*)[72])(sA + 4 * 9216);
  f16 (*B1l)[72] = (f16 (*)[72])(sA + 5 * 9216);
  f16 (*Y8h)[72] = (f16 (*)[72])(sA + 6 * 9216);
  f16 (*Y8l)[72] = (f16 (*)[72])(sA + 7 * 9216);
  f16 (*Ybh)[72] = (f16 (*)[72])(sA + 8 * 9216);
  f16 (*Ybl)[72] = (f16 (*)[72])(sA + 9 * 9216);

  int tau = blockIdx.x;
  int e = tau + 1;
  int a = e >> 3, b = e & 7;
  int wave = t >> 6, lane = t & 63;
  int tn = wave >> 2, tm = wave & 3;       // 4x4 grid of 16x16 tiles
  int kg = lane >> 4, fr = lane & 15;

  auto mm = [&](f16 (*Ph)[72], f16 (*Pl)[72], f16 (*Qh)[72], f16 (*Ql)[72],
                f16 (*Dh)[72], f16 (*Dl)[72]) {
    f32x4 acc = {};
    #pragma unroll
    for (int kk = 0; kk < 2; ++kk) {
      f16x8 ah = *(const f16x8*)&Ph[tn * 16 + fr][kk * 32 + kg * 8];
      f16x8 al = *(const f16x8*)&Pl[tn * 16 + fr][kk * 32 + kg * 8];
      f16x8 bh = *(const f16x8*)&Qh[tm * 16 + fr][kk * 32 + kg * 8];
      f16x8 bl = *(const f16x8*)&Ql[tm * 16 + fr][kk * 32 + kg * 8];
      acc = __builtin_amdgcn_mfma_f32_16x16x32_f16(ah, bh, acc, 0, 0, 0);
      acc = __builtin_amdgcn_mfma_f32_16x16x32_f16(ah, bl, acc, 0, 0, 0);
      acc = __builtin_amdgcn_mfma_f32_16x16x32_f16(al, bh, acc, 0, 0, 0);
    }
    #pragma unroll
    for (int r = 0; r < 4; ++r) {
      float v = acc[r];
      f16 h = (f16)v, l = (f16)(v - (float)h);
      Dh[tn * 16 + kg * 4 + r][tm * 16 + fr] = h;
      Dl[tn * 16 + kg * 4 + r][tm * 16 + fr] = l;
    }
    __syncthreads();
  };
  auto cpy2 = [&](f16 (*Sh)[72], f16 (*Sl)[72], f16 (*Dh)[72], f16 (*Dl)[72]) {
    const unsigned* sh = (const unsigned*)Sh; unsigned* dh = (unsigned*)Dh;
    const unsigned* sl = (const unsigned*)Sl; unsigned* dl = (unsigned*)Dl;
    for (int idx = t; idx < 2304; idx += 1024) { dh[idx] = sh[idx]; dl[idx] = sl[idx]; }
  };

  for (int idx = t; idx < 4096; idx += 1024) {
    float v = A[idx];
    int r = idx >> 6, c2 = idx & 63;
    f16 h = (f16)v, l = (f16)(v - (float)h);
    Ah[r][c2] = h;  Al[r][c2] = l;
    B0h[c2][r] = h; B0l[c2][r] = l;
  }
  __syncthreads();

  f16 (*curH)[72] = B0h; f16 (*curL)[72] = B0l;
  f16 (*othH)[72] = B1h; f16 (*othL)[72] = B1l;
  auto swp = [&]() {
    f16 (*tH)[72] = curH; curH = othH; othH = tH;
    f16 (*tL)[72] = curL; curL = othL; othL = tL;
  };

  if (b == 1) cpy2(curH, curL, Ybh, Ybl);

  int loMax = (a >= 1) ? 8 : b;
  for (int i = 2; i <= loMax; ++i) {
    mm(curH, curL, Ah, Al, othH, othL);
    swp();
    if (i == b) cpy2(curH, curL, Ybh, Ybl);
    if (i == 8) cpy2(curH, curL, Y8h, Y8l);
  }

  f16 (*Rh)[72]; f16 (*Rl)[72]; bool tr;
  if (a == 0) {
    Rh = curH; Rl = curL; tr = true;                // result = Y_b^T
  } else {
    for (int idx = t; idx < 4096; idx += 1024) {
      int i = idx >> 6, j = idx & 63;
      othH[i][j] = curH[j][i];
      othL[i][j] = curL[j][i];
    }
    swp();
    __syncthreads();
    for (int a2 = 2; a2 <= a; ++a2) {               // H_{a+1} = mfma(H_a, Y8)
      mm(curH, curL, Y8h, Y8l, othH, othL);
      swp();
    }
    if (b >= 1) {                                   // P = mfma(H_a, Y_b)
      mm(curH, curL, Ybh, Ybl, othH, othL);
      swp();
    }
    Rh = curH; Rl = curL; tr = false;
  }

  for (int idx = t; idx < 4096; idx += 1024) {
    int wn = idx >> 6, m = idx & 63;
    f16 h = tr ? Rh[m][wn] : Rh[wn][m];
    f16 l = tr ? Rl[m][wn] : Rl[wn][m];
    f16* wrow = W16 + ((size_t)(tau * 64 + wn)) * 256;
    wrow[64 + m] = h; wrow[128 + m] = l; wrow[192 + m] = h;
    if (tau == 63) A64[idx] = (float)h + (float)l;
  }
  if (t < 64) {
    float s = 0.f;
    #pragma unroll 8
    for (int m = 0; m < 64; ++m) {
      float pv = tr ? ((float)Rh[m][t] + (float)Rl[m][t])
                    : ((float)Rh[t][m] + (float)Rl[t][m]);
      s += pv * Bm[m];
    }
    if (tau < 63) Kv[(tau + 1) * 64 + t] = s;
    else          Kv[t] = Bm[t];
  }
}

// ---------------- kB: Kmat rows | fused conv+scan (LDS-broadcast) ----------------
__global__ __launch_bounds__(256) void kB_prep(
    const float* __restrict__ inp, const float* __restrict__ Kv,
    const float* __restrict__ A64,
    f16* __restrict__ R16, f16* __restrict__ W16)
{
  __shared__ __align__(16) float sm[64 * 66];
  int t = threadIdx.x;
  int b = blockIdx.x;
  if (b < 64) {
    int tau = b;
    for (int idx = t; idx < 4096; idx += 256) sm[idx] = Kv[idx];
    __syncthreads();
    int wn = t & 63, kq = t >> 6;
    f16* wrow = W16 + ((size_t)(tau * 64 + wn)) * 256 + kq * 16;
    #pragma unroll
    for (int ki = 0; ki < 16; ++ki) {
      int k = kq * 16 + ki;
      wrow[ki] = (f16)((k <= tau) ? sm[(tau - k) * 64 + wn] : 0.0f);
    }
  } else {
    int wv = t >> 6, L = t & 63;
    int q = (b - 64) * 4 + wv;
    float* xs = sm + wv * 144;
    float* vs = xs + 72;
    float ar[64], kvr[64];
    #pragma unroll
    for (int m = 0; m < 64; m += 4) {
      f32x4 v4 = *(const f32x4*)(A64 + L * 64 + m);
      ar[m] = v4.x; ar[m + 1] = v4.y; ar[m + 2] = v4.z; ar[m + 3] = v4.w;
    }
    #pragma unroll
    for (int k = 0; k < 64; ++k) kvr[k] = Kv[(63 - k) * 64 + L];
    float x = 0.f;
    float v = inp[(size_t)L * 512 + q];
    for (int j = 0; j < 32; ++j) {
      float vn = (j < 31) ? inp[(size_t)((j + 1) * 64 + L) * 512 + q] : 0.f;
      f16 hh = (f16)x, ll = (f16)(x - (float)hh);
      f16* row = R16 + ((size_t)(j * 512 + q)) * 256;
      row[64 + L] = hh; row[128 + L] = hh; row[192 + L] = ll;
      xs[L] = x;
      vs[L] = v;
      float a0 = 0.f, a1 = 0.f, c0 = 0.f, c1 = 0.f;
      #pragma unroll
      for (int m = 0; m < 64; m += 4) {
        f32x4 xv = *(const f32x4*)(xs + m);   // same-addr broadcast, conflict-free
        f32x4 vv = *(const f32x4*)(vs + m);
        a0 += ar[m] * xv.x + ar[m + 1] * xv.y;
        a1 += ar[m + 2] * xv.z + ar[m + 3] * xv.w;
        c0 += kvr[m] * vv.x + kvr[m + 1] * vv.y;
        c1 += kvr[m + 2] * vv.z + kvr[m + 3] * vv.w;
      }
      x = (a0 + a1) + (c0 + c1);
      v = vn;
    }
  }
}

// ---------------- kC: C[16384 x 4096] = R16 @ W16^T ----------------
// BK=32, 2 buffers (16KB each: A 8KB + B 8KB), counted vmcnt(4), raw barriers.
// LDS rows 64B: LDS[row][slot] holds G[row][slot ^ ((row>>1)&3)] (slot = 8 f16).
#define STAGE32(ks, dbuf)                                                       \
  { _Pragma("unroll")                                                           \
    for (int it = 0; it < 2; ++it) {                                            \
      __builtin_amdgcn_global_load_lds(                                         \
        (const __attribute__((address_space(1))) void*)                         \
          (R16 + ((size_t)(mtb + w32 + it * 16 + l4)) * 256 + (ks) * 32 + swc32),\
        (__attribute__((address_space(3))) void*)((dbuf) + w * 1024 + it * 512),\
        16, 0, 0);                                                              \
      __builtin_amdgcn_global_load_lds(                                         \
        (const __attribute__((address_space(1))) void*)                         \
          (W16 + ((size_t)(ntb + w32 + it * 16 + l4)) * 256 + (ks) * 32 + swc32),\
        (__attribute__((address_space(3))) void*)((dbuf) + 4096 + w * 1024 + it * 512),\
        16, 0, 0);                                                              \
    } }

#define KSTEP32(sbuf)                                                           \
  { f16x8 af[4], bf[4];                                                         \
    _Pragma("unroll")                                                           \
    for (int i = 0; i < 4; ++i) {                                               \
      af[i] = *(const f16x8*)((sbuf) + (wr * 64 + i * 16 + fr) * 32 + scol);    \
      bf[i] = *(const f16x8*)((sbuf) + 4096 + (wc * 64 + i * 16 + fr) * 32 + scol);\
    }                                                                           \
    _Pragma("unroll")                                                           \
    for (int mi = 0; mi < 4; ++mi)                                              \
      _Pragma("unroll")                                                         \
      for (int ni = 0; ni < 4; ++ni)                                            \
        acc[mi][ni] = __builtin_amdgcn_mfma_f32_16x16x32_f16(                   \
            af[mi], bf[ni], acc[mi][ni], 0, 0, 0);                              \
  }

#define WAITN(n) asm volatile("s_waitcnt vmcnt(" #n ")" ::: "memory")
#define BAR()                                                                   \
  { __builtin_amdgcn_sched_barrier(0); __builtin_amdgcn_s_barrier();            \
    __builtin_amdgcn_sched_barrier(0); }

__global__ __launch_bounds__(256, 4) void kC_gemm(
    const f16* __restrict__ R16, const f16* __restrict__ W16,
    float* __restrict__ out)
{
  __shared__ __align__(16) char smem[34816];     // 2x16KB staging; epilogue alias
  f16* b0v = (f16*)smem;
  f16* b1v = b0v + 8192;
  float (*stg)[68] = (float (*)[68])smem;        // 34816B, aliased

  int wg = blockIdx.x;
  int swz = (wg & 7) * 512 + (wg >> 3);          // XCD-contiguous mt ranges
  int mt = swz >> 5, nt = swz & 31;
  int t = threadIdx.x, w = t >> 6, lane = t & 63;
  int wr = w >> 1, wc = w & 1;
  int kg = lane >> 4, fr = lane & 15;

  // staging indices (BK=32, 64B rows, 4 lanes/row)
  int l4 = lane >> 2;
  int swc32 = 8 * ((lane & 3) ^ ((lane >> 3) & 3));   // pre-swizzled src col (f16)
  int w32 = w * 32;
  int mtb = mt * 128, ntb = nt * 128;
  int scol = 8 * (kg ^ ((fr >> 1) & 3));              // swizzle-matched read col

  f32x4 acc[4][4] = {};

  STAGE32(0, b0v);
  STAGE32(1, b1v); WAITN(4); BAR(); KSTEP32(b0v); BAR();
  STAGE32(2, b0v); WAITN(4); BAR(); KSTEP32(b1v); BAR();
  STAGE32(3, b1v); WAITN(4); BAR(); KSTEP32(b0v); BAR();
  STAGE32(4, b0v); WAITN(4); BAR(); KSTEP32(b1v); BAR();
  STAGE32(5, b1v); WAITN(4); BAR(); KSTEP32(b0v); BAR();
  STAGE32(6, b0v); WAITN(4); BAR(); KSTEP32(b1v); BAR();
  STAGE32(7, b1v); WAITN(4); BAR(); KSTEP32(b0v); BAR();
  WAITN(0); BAR(); KSTEP32(b1v); BAR();

  // epilogue: per tau-half, stage 128x64 f32 tile in LDS, write 32KB contiguous
  // (PLAIN stores this round -- nt vs plain A/B; fillBuffer's cached stores
  //  sustain 6.8 TB/s on this buffer vs our ~4 TB/s through the nt path.)
  int j = mt >> 2, q0 = (mt & 3) * 128;
  #pragma unroll
  for (int half = 0; half < 2; ++half) {
    if (wc == half) {
      #pragma unroll
      for (int mi = 0; mi < 4; ++mi)
        #pragma unroll
        for (int ni = 0; ni < 4; ++ni)
          #pragma unroll
          for (int r = 0; r < 4; ++r)
            stg[wr * 64 + mi * 16 + kg * 4 + r][ni * 16 + fr] = acc[mi][ni][r];
    }
    asm volatile("s_waitcnt lgkmcnt(0)" ::: "memory");
    BAR();
    int tau_g = nt * 2 + half;
    float* obase = out + (size_t)j * 2097152 + (size_t)tau_g * 32768 + (size_t)q0 * 64;
    #pragma unroll
    for (int it = 0; it < 8; ++it) {
      int fi = it * 1024 + t * 4;
      int rr = fi >> 6, cc = fi & 63;
      *(f32x4*)(obase + fi) = *(const f32x4*)(&stg[rr][cc]);
    }
    BAR();
  }
}

extern "C" void kernel_launch(void* const* d_in, const int* in_sizes, int n_in,
                              void* d_out, int out_size, void* d_ws, size_t ws_size,
                              hipStream_t stream)
{
  (void)in_sizes; (void)n_in; (void)out_size; (void)ws_size;
  const float* inp = (const float*)d_in[0];   // (2048, 8, 64) fp32
  const float* A   = (const float*)d_in[1];   // (64, 64) fp32
  const float* Bm  = (const float*)d_in[2];   // (64, 1) fp32
  float* out = (float*)d_out;                 // (2048, 8, 64, 64) fp32

  float* ws = (float*)d_ws;
  float* A64 = ws;                            // 4096 f32   (16 KB)
  float* Kv  = ws + 4096;                     // 4096 f32   (16 KB)
  f16*  W16  = (f16*)(ws + 8192);             // 4096*256 f16 (2 MB)
  f16*  R16  = (f16*)((char*)d_ws + 2129920); // 16384*256 f16 (8 MB)

  hipLaunchKernelGGL(kA_pow,  dim3(192),  dim3(1024), 0, stream, A, Bm, inp, A64, Kv, W16, R16);
  hipLaunchKernelGGL(kB_prep, dim3(192),  dim3(256),  0, stream, inp, Kv, A64, R16, W16);
  hipLaunchKernelGGL(kC_gemm, dim3(4096), dim3(256),  0, stream, R16, W16, out);
}